// Round 1
// baseline (183.230 us; speedup 1.0000x reference)
//
#include <hip/hip_runtime.h>

// SelfAttention: out = softmax(QK^T*s + fw_mask) V + softmax(QK^T*s + bw_mask) V
// B=8, L=2048, D=64, fp32 in/out.  bf16 MFMA flash-style, NO online max
// (scores bounded, exp can't overflow fp32; -1e9 mask == hard 0 in fp32).
//
// Decomposition: WG = 256 thr = 4 waves; WG owns 16 Q rows; wave w owns keys
// [512w,512w+512) in 16 blocks of 32 keys. Partials combine linearly (no max
// state), reduced across waves through LDS at the end. No barrier in main loop.
//
// MFMA 16x16x32 bf16 layouts (per cdna_hip_programming.md §3, m89/m120):
//   A: elem j of lane l = A[l&15][(l>>4)*8+j]
//   B: elem j of lane l = B[(l>>4)*8+j][l&15]
//   C/D: elem r of lane l = D[(l>>4)*4+r][l&15]
// S computed transposed (S^T = K·Q^T) so K,Q frags load straight from global.
// PV as O^T += V^T · P^T; V^T staged in LDS (pair-packed writes), P round-
// tripped through LDS (C-layout -> B-layout).

typedef __attribute__((ext_vector_type(8))) short short8;
typedef __attribute__((ext_vector_type(4))) float f32x4;

union Frag {
    short8 s;
    unsigned u[4];
    uint4 u4;
};

#define MFMA16(A, B, C) __builtin_amdgcn_mfma_f32_16x16x32_bf16((A), (B), (C), 0, 0, 0)

static constexpr int BB = 8, LL = 2048, DD = 64;
// fold 1/sqrt(64) and log2(e) into Q so exp becomes exp2
static constexpr float QSCALE = 0.125f * 1.44269504088896340736f;

// pack two f32 -> bf16x2 (round-half-up: +0x8000 then take high 16 via v_perm)
__device__ __forceinline__ unsigned pk2(float a, float b) {
    unsigned ua = __builtin_bit_cast(unsigned, a) + 0x8000u;
    unsigned ub = __builtin_bit_cast(unsigned, b) + 0x8000u;
    return __builtin_amdgcn_perm(ub, ua, 0x07060302u);
}

__global__ __launch_bounds__(256)
void attn_fused(const float* __restrict__ Q, const float* __restrict__ K,
                const float* __restrict__ V, float* __restrict__ O) {
    // LDS (uints):
    //   [0,5120)      VT per wave: [64 d][20] (16 used = 32 keys bf16-paired, +4 pad)
    //   [5120,7680)   P  per wave: [2 sides][16 i][20] (16 used, +4 pad)
    //   epilogue (after barrier, aliases the above):
    //   [0,8192)      red:  [4 w][2 s][64 d][16 i] f32   (O^T partials)
    //   [8192,8320)   lred: [4 w][2 s][16 i] f32
    __shared__ unsigned smem[8448];

    const int tid  = threadIdx.x;
    const int w    = tid >> 6;
    const int lane = tid & 63;
    const int col  = lane & 15;
    const int quad = lane >> 4;

    const int b  = blockIdx.x >> 7;
    const int i0 = (blockIdx.x & 127) << 4;

    const float* Qb = Q + (size_t)(b * LL + i0) * DD;
    const float* Kb = K + (size_t)b * LL * DD;
    const float* Vb = V + (size_t)b * LL * DD;

    unsigned* VT = smem + w * 1280;
    unsigned* Pb = smem + 5120 + w * 640;

    // ---- Q fragments (B operand of S^T), pre-scaled: Q[i0+col][d], d=quad*8+j (+32)
    Frag qf[2];
    {
        const float* qr = Qb + col * DD + quad * 8;
        float4 a0 = *(const float4*)(qr + 0);
        float4 a1 = *(const float4*)(qr + 4);
        float4 a2 = *(const float4*)(qr + 32);
        float4 a3 = *(const float4*)(qr + 36);
        qf[0].u[0] = pk2(a0.x * QSCALE, a0.y * QSCALE);
        qf[0].u[1] = pk2(a0.z * QSCALE, a0.w * QSCALE);
        qf[0].u[2] = pk2(a1.x * QSCALE, a1.y * QSCALE);
        qf[0].u[3] = pk2(a1.z * QSCALE, a1.w * QSCALE);
        qf[1].u[0] = pk2(a2.x * QSCALE, a2.y * QSCALE);
        qf[1].u[1] = pk2(a2.z * QSCALE, a2.w * QSCALE);
        qf[1].u[2] = pk2(a3.x * QSCALE, a3.y * QSCALE);
        qf[1].u[3] = pk2(a3.z * QSCALE, a3.w * QSCALE);
    }

    Frag ones;  // bf16 1.0 pairs; A=ones turns MFMA into column-sum -> l
    ones.u[0] = ones.u[1] = ones.u[2] = ones.u[3] = 0x3F803F80u;

    f32x4 zero = {0.f, 0.f, 0.f, 0.f};
    f32x4 ot[2][4];   // [side][d-block c]  O^T accumulators (s=0 fw, s=1 bw)
    f32x4 lacc[2];    // l accumulators (all 4 regs identical rows)
    lacc[0] = zero; lacc[1] = zero;
    #pragma unroll
    for (int s = 0; s < 2; ++s)
        #pragma unroll
        for (int c = 0; c < 4; ++c) ot[s][c] = zero;

    const int kbase = w << 9;          // this wave's key range start
    const int dj0   = i0 & ~31;        // the single mixed (diagonal) block

    for (int blk = 0; blk < 16; ++blk) {
        const int j0 = kbase + (blk << 5);

        // ---- K fragments (A operand): K[j0+16f+col][d]
        Frag ka[2][2];
        #pragma unroll
        for (int f = 0; f < 2; ++f) {
            const float* kr = Kb + (size_t)(j0 + f * 16 + col) * DD + quad * 8;
            float4 c0 = *(const float4*)(kr + 0);
            float4 c1 = *(const float4*)(kr + 4);
            float4 c2 = *(const float4*)(kr + 32);
            float4 c3 = *(const float4*)(kr + 36);
            ka[f][0].u[0] = pk2(c0.x, c0.y);
            ka[f][0].u[1] = pk2(c0.z, c0.w);
            ka[f][0].u[2] = pk2(c1.x, c1.y);
            ka[f][0].u[3] = pk2(c1.z, c1.w);
            ka[f][1].u[0] = pk2(c2.x, c2.y);
            ka[f][1].u[1] = pk2(c2.z, c2.w);
            ka[f][1].u[2] = pk2(c3.x, c3.y);
            ka[f][1].u[3] = pk2(c3.z, c3.w);
        }

        // ---- stage V transposed into VT: lane covers keys {2col,2col+1} x 4 d-chunks
        #pragma unroll
        for (int u = 0; u < 4; ++u) {
            const int d0 = u * 16 + quad * 4;
            const float* va = Vb + (size_t)(j0 + 2 * col) * DD + d0;
            float4 x = *(const float4*)(va);
            float4 y = *(const float4*)(va + DD);
            VT[(d0 + 0) * 20 + col] = pk2(x.x, y.x);
            VT[(d0 + 1) * 20 + col] = pk2(x.y, y.y);
            VT[(d0 + 2) * 20 + col] = pk2(x.z, y.z);
            VT[(d0 + 3) * 20 + col] = pk2(x.w, y.w);
        }

        // ---- S^T = K · (Q*scale)^T  (rows = keys, cols = queries)
        f32x4 st0 = zero, st1 = zero;
        st0 = MFMA16(ka[0][0].s, qf[0].s, st0);
        st0 = MFMA16(ka[0][1].s, qf[1].s, st0);
        st1 = MFMA16(ka[1][0].s, qf[0].s, st1);
        st1 = MFMA16(ka[1][1].s, qf[1].s, st1);

        float p0[4], p1[4];
        #pragma unroll
        for (int r = 0; r < 4; ++r) { p0[r] = exp2f(st0[r]); p1[r] = exp2f(st1[r]); }

        // ---- mask + store P (bf16, row-major [i][key]) into side buffer(s)
        bool doF, doB;
        if (j0 == dj0) {
            const int ig = i0 + col;
            unsigned* prowF = Pb + col * 20 + quad * 2;
            unsigned* prowB = prowF + 320;
            float m0[4], m1[4];
            #pragma unroll
            for (int r = 0; r < 4; ++r) {
                const int jg = j0 + 4 * quad + r;
                m0[r] = (jg >= ig) ? p0[r] : 0.f;
                m1[r] = (jg + 16 >= ig) ? p1[r] : 0.f;
            }
            prowF[0] = pk2(m0[0], m0[1]);
            prowF[1] = pk2(m0[2], m0[3]);
            prowF[8] = pk2(m1[0], m1[1]);
            prowF[9] = pk2(m1[2], m1[3]);
            #pragma unroll
            for (int r = 0; r < 4; ++r) {
                const int jg = j0 + 4 * quad + r;
                m0[r] = (jg <= ig) ? p0[r] : 0.f;
                m1[r] = (jg + 16 <= ig) ? p1[r] : 0.f;
            }
            prowB[0] = pk2(m0[0], m0[1]);
            prowB[1] = pk2(m0[2], m0[3]);
            prowB[8] = pk2(m1[0], m1[1]);
            prowB[9] = pk2(m1[2], m1[3]);
            doF = true; doB = true;
        } else if (j0 < i0) {
            unsigned* prowB = Pb + 320 + col * 20 + quad * 2;
            prowB[0] = pk2(p0[0], p0[1]);
            prowB[1] = pk2(p0[2], p0[3]);
            prowB[8] = pk2(p1[0], p1[1]);
            prowB[9] = pk2(p1[2], p1[3]);
            doF = false; doB = true;
        } else {
            unsigned* prowF = Pb + col * 20 + quad * 2;
            prowF[0] = pk2(p0[0], p0[1]);
            prowF[1] = pk2(p0[2], p0[3]);
            prowF[8] = pk2(p1[0], p1[1]);
            prowF[9] = pk2(p1[2], p1[3]);
            doF = true; doB = false;
        }

        // ---- V^T fragments (A operand): VT[16c+col][key=quad*8+j]
        Frag vfr[4];
        #pragma unroll
        for (int c = 0; c < 4; ++c)
            vfr[c].u4 = *(const uint4*)(VT + (16 * c + col) * 20 + quad * 4);

        // ---- PV: O^T[s] += V^T · P^T ; l[s] += ones · P^T
        if (doF) {
            Frag pf; pf.u4 = *(const uint4*)(Pb + col * 20 + quad * 4);
            lacc[0] = MFMA16(ones.s, pf.s, lacc[0]);
            #pragma unroll
            for (int c = 0; c < 4; ++c) ot[0][c] = MFMA16(vfr[c].s, pf.s, ot[0][c]);
        }
        if (doB) {
            Frag pg; pg.u4 = *(const uint4*)(Pb + 320 + col * 20 + quad * 4);
            lacc[1] = MFMA16(ones.s, pg.s, lacc[1]);
            #pragma unroll
            for (int c = 0; c < 4; ++c) ot[1][c] = MFMA16(vfr[c].s, pg.s, ot[1][c]);
        }
    }

    // ---- cross-wave reduction (partials add linearly: no max state)
    __syncthreads();
    float* red  = (float*)smem;            // [4][2][64][16]
    float* lred = (float*)(smem + 8192);   // [4][2][16]
    #pragma unroll
    for (int s = 0; s < 2; ++s)
        #pragma unroll
        for (int c = 0; c < 4; ++c)
            #pragma unroll
            for (int r = 0; r < 4; ++r)
                red[((w * 2 + s) * 64 + 16 * c + 4 * quad + r) * 16 + col] = ot[s][c][r];
    if (lane < 16) {
        lred[(w * 2 + 0) * 16 + col] = lacc[0][0];
        lred[(w * 2 + 1) * 16 + col] = lacc[1][0];
    }
    __syncthreads();

    const int ri = tid >> 4;            // output row 0..15
    const int db = (tid & 15) << 2;     // output d base (float4)
    float lf = 0.f, lb = 0.f;
    #pragma unroll
    for (int w2 = 0; w2 < 4; ++w2) {
        lf += lred[(w2 * 2 + 0) * 16 + ri];
        lb += lred[(w2 * 2 + 1) * 16 + ri];
    }
    const float rf = 1.0f / lf;
    const float rb = 1.0f / lb;
    float acc[4];
    #pragma unroll
    for (int kk = 0; kk < 4; ++kk) {
        float af = 0.f, ab = 0.f;
        #pragma unroll
        for (int w2 = 0; w2 < 4; ++w2) {
            af += red[((w2 * 2 + 0) * 64 + db + kk) * 16 + ri];
            ab += red[((w2 * 2 + 1) * 64 + db + kk) * 16 + ri];
        }
        acc[kk] = af * rf + ab * rb;
    }
    float4 o = {acc[0], acc[1], acc[2], acc[3]};
    *(float4*)(O + (size_t)(b * LL + i0 + ri) * DD + db) = o;
}

extern "C" void kernel_launch(void* const* d_in, const int* in_sizes, int n_in,
                              void* d_out, int out_size, void* d_ws, size_t ws_size,
                              hipStream_t stream) {
    const float* q = (const float*)d_in[0];
    const float* k = (const float*)d_in[1];
    const float* v = (const float*)d_in[2];
    float* o = (float*)d_out;
    (void)in_sizes; (void)n_in; (void)out_size; (void)d_ws; (void)ws_size;
    attn_fused<<<dim3(BB * (LL / 16)), dim3(256), 0, stream>>>(q, k, v, o);
}

// Round 2
// 100.875 us; speedup vs baseline: 1.8164x; 1.8164x over previous
//
#include <hip/hip_runtime.h>

// SelfAttention: out = softmax(QK^T*s + fw)V + softmax(QK^T*s + bw)V
// B=8, L=2048, D=64, fp32 in/out. bf16 MFMA, no online max (scores bounded;
// -1e9 mask == hard zero in fp32 exp).
//
// v2: pre-pack K (bf16 row-major) and V (bf16 TRANSPOSED [b][d][key]) into
// d_ws so the hot loop loads MFMA fragments directly (8 uint4/wave/block,
// explicitly double-buffered). 32 Q rows per WG (2 q-tiles share K/V frags),
// XCD-swizzled batches (b = blockIdx&7) so each batch's 4MB packed K/V pins
// in one XCD L2. Falls back to the (slow, correct) v1 kernel if ws_size<4MB.
//
// MFMA 16x16x32 bf16 layouts (validated in R1, absmax 1.6e-2):
//   A: elem j of lane l = A[l&15][(l>>4)*8+j]
//   B: elem j of lane l = B[(l>>4)*8+j][l&15]
//   C/D: elem r of lane l = D[(l>>4)*4+r][l&15]

typedef __attribute__((ext_vector_type(8))) short short8;
typedef __attribute__((ext_vector_type(4))) float f32x4;
typedef unsigned short u16t;

union Frag {
    short8 s;
    unsigned u[4];
    uint4 u4;
};

#define MFMA16(A, B, C) __builtin_amdgcn_mfma_f32_16x16x32_bf16((A), (B), (C), 0, 0, 0)

static constexpr int BB = 8, LL = 2048, DD = 64;
static constexpr float QSCALE = 0.125f * 1.44269504088896340736f;  // /sqrt(64) * log2(e)

// pack two f32 -> bf16x2 (a=low, b=high); round-half-up (+0x8000, keep hi16)
__device__ __forceinline__ unsigned pk2(float a, float b) {
    unsigned ua = __builtin_bit_cast(unsigned, a) + 0x8000u;
    unsigned ub = __builtin_bit_cast(unsigned, b) + 0x8000u;
    return __builtin_amdgcn_perm(ub, ua, 0x07060302u);
}

// ---------------------------------------------------------------- prepack ---
// grid 512x256: blocks [0,256) transpose V tiles, [256,512) pack K.
__global__ __launch_bounds__(256)
void prepack(const float* __restrict__ K, const float* __restrict__ V,
             u16t* __restrict__ Kp, u16t* __restrict__ VTp) {
    const int t = threadIdx.x;
    if (blockIdx.x < 256) {
        // V tile: batch b, keys [k0, k0+64) -> VTp[b][d][key]
        const int b  = blockIdx.x >> 5;
        const int k0 = (blockIdx.x & 31) << 6;
        __shared__ unsigned LT[64 * 34];  // [d][key-pair m], pad 34
        const int m  = t >> 3;            // key pair 0..31
        const int d0 = (t & 7) * 8;
        const float* vr = V + ((size_t)(b * LL + k0 + 2 * m)) * DD + d0;
        float4 x0 = *(const float4*)(vr + 0);
        float4 x1 = *(const float4*)(vr + 4);
        float4 y0 = *(const float4*)(vr + DD + 0);
        float4 y1 = *(const float4*)(vr + DD + 4);
        LT[(d0 + 0) * 34 + m] = pk2(x0.x, y0.x);
        LT[(d0 + 1) * 34 + m] = pk2(x0.y, y0.y);
        LT[(d0 + 2) * 34 + m] = pk2(x0.z, y0.z);
        LT[(d0 + 3) * 34 + m] = pk2(x0.w, y0.w);
        LT[(d0 + 4) * 34 + m] = pk2(x1.x, y1.x);
        LT[(d0 + 5) * 34 + m] = pk2(x1.y, y1.y);
        LT[(d0 + 6) * 34 + m] = pk2(x1.z, y1.z);
        LT[(d0 + 7) * 34 + m] = pk2(x1.w, y1.w);
        __syncthreads();
        const int d = t >> 2;
        const int c = t & 3;
        const unsigned* lp = &LT[d * 34 + c * 8];
        uint2 r0 = *(const uint2*)(lp + 0);
        uint2 r1 = *(const uint2*)(lp + 2);
        uint2 r2 = *(const uint2*)(lp + 4);
        uint2 r3 = *(const uint2*)(lp + 6);
        u16t* orow = VTp + ((size_t)(b * DD + d)) * LL + k0 + c * 16;
        *((uint4*)orow + 0) = make_uint4(r0.x, r0.y, r1.x, r1.y);
        *((uint4*)orow + 1) = make_uint4(r2.x, r2.y, r3.x, r3.y);
    } else {
        // K flat pack: 16 elems/thread
        const int idx = blockIdx.x - 256;
        const size_t base = ((size_t)idx * 256 + t) * 16;
        const float4* kin = (const float4*)(K + base);
        float4 a0 = kin[0], a1 = kin[1], a2 = kin[2], a3 = kin[3];
        uint4 o0 = make_uint4(pk2(a0.x, a0.y), pk2(a0.z, a0.w),
                              pk2(a1.x, a1.y), pk2(a1.z, a1.w));
        uint4 o1 = make_uint4(pk2(a2.x, a2.y), pk2(a2.z, a2.w),
                              pk2(a3.x, a3.y), pk2(a3.z, a3.w));
        *((uint4*)(Kp + base) + 0) = o0;
        *((uint4*)(Kp + base) + 1) = o1;
    }
}

// ------------------------------------------------------------------- main ---
__global__ __launch_bounds__(256, 2)
void attn_v2(const float* __restrict__ Q, const u16t* __restrict__ Kp,
             const u16t* __restrict__ VTp, float* __restrict__ O) {
    // LDS union:
    //   main loop:  P region, wave w at [w*1280, w*1280+1280) u32:
    //               [tile t][side s] -> +t*640+s*320, each [16 q][20] u32
    //   epilogue:   red [4 w][32 q][68 d] f32 = 8704 f  (one side per pass)
    //               lred [4 w][2 s][32 q] f32 at u32 offset 8704
    __shared__ __align__(16) unsigned lds[8960];

    const int tid  = threadIdx.x;
    const int w    = tid >> 6;
    const int lane = tid & 63;
    const int col  = lane & 15;
    const int quad = lane >> 4;

    const int b     = blockIdx.x & 7;    // batch == XCD slot (L2 pinning)
    const int it    = blockIdx.x >> 3;   // 0..63
    const int ibase = it << 5;           // 32 Q rows per WG

    const float* Qb  = Q + ((size_t)(b * LL + ibase)) * DD;
    const u16t*  Kb  = Kp + (size_t)b * LL * DD;
    const u16t*  Vb  = VTp + (size_t)b * DD * LL;
    unsigned*    Pw  = lds + w * 1280;

    // ---- Q fragments (B operand), pre-scaled, per tile
    Frag qf[2][2];
    #pragma unroll
    for (int t = 0; t < 2; ++t) {
        const float* qr = Qb + (16 * t + col) * DD + quad * 8;
        float4 a0 = *(const float4*)(qr + 0);
        float4 a1 = *(const float4*)(qr + 4);
        float4 a2 = *(const float4*)(qr + 32);
        float4 a3 = *(const float4*)(qr + 36);
        qf[t][0].u[0] = pk2(a0.x * QSCALE, a0.y * QSCALE);
        qf[t][0].u[1] = pk2(a0.z * QSCALE, a0.w * QSCALE);
        qf[t][0].u[2] = pk2(a1.x * QSCALE, a1.y * QSCALE);
        qf[t][0].u[3] = pk2(a1.z * QSCALE, a1.w * QSCALE);
        qf[t][1].u[0] = pk2(a2.x * QSCALE, a2.y * QSCALE);
        qf[t][1].u[1] = pk2(a2.z * QSCALE, a2.w * QSCALE);
        qf[t][1].u[2] = pk2(a3.x * QSCALE, a3.y * QSCALE);
        qf[t][1].u[3] = pk2(a3.z * QSCALE, a3.w * QSCALE);
    }

    Frag ones;
    ones.u[0] = ones.u[1] = ones.u[2] = ones.u[3] = 0x3F803F80u;

    f32x4 zero = {0.f, 0.f, 0.f, 0.f};
    f32x4 ot[2][2][4];   // [tile][side][d-chunk]
    f32x4 lacc[2][2];
    #pragma unroll
    for (int t = 0; t < 2; ++t)
        #pragma unroll
        for (int s = 0; s < 2; ++s) {
            lacc[t][s] = zero;
            #pragma unroll
            for (int c = 0; c < 4; ++c) ot[t][s][c] = zero;
        }

    const int kbase = w << 9;

    // fragment loaders (all contiguous 16B, bf16 direct)
    Frag ka[4], vf[4], kan[4], vfn[4];
    {
        const int j0 = kbase;
        #pragma unroll
        for (int f = 0; f < 2; ++f)
            #pragma unroll
            for (int h = 0; h < 2; ++h)
                ka[f * 2 + h].u4 = *(const uint4*)(Kb + (size_t)(j0 + 16 * f + col) * DD + h * 32 + quad * 8);
        #pragma unroll
        for (int c = 0; c < 4; ++c)
            vf[c].u4 = *(const uint4*)(Vb + (size_t)(16 * c + col) * LL + j0 + quad * 8);
    }

    for (int blk = 0; blk < 16; ++blk) {
        const int j0 = kbase + (blk << 5);
        const int jn = (blk == 15) ? kbase : (j0 + 32);  // dummy reload last iter
        // ---- prefetch next block (batched; hidden behind compute)
        #pragma unroll
        for (int f = 0; f < 2; ++f)
            #pragma unroll
            for (int h = 0; h < 2; ++h)
                kan[f * 2 + h].u4 = *(const uint4*)(Kb + (size_t)(jn + 16 * f + col) * DD + h * 32 + quad * 8);
        #pragma unroll
        for (int c = 0; c < 4; ++c)
            vfn[c].u4 = *(const uint4*)(Vb + (size_t)(16 * c + col) * LL + jn + quad * 8);

        // ---- S^T = K · (Qs)^T for both q-tiles (rows=keys, cols=queries)
        f32x4 st[2][2];
        #pragma unroll
        for (int t = 0; t < 2; ++t)
            #pragma unroll
            for (int f = 0; f < 2; ++f) {
                f32x4 acc = zero;
                acc = MFMA16(ka[f * 2 + 0].s, qf[t][0].s, acc);
                acc = MFMA16(ka[f * 2 + 1].s, qf[t][1].s, acc);
                st[t][f] = acc;
            }

        const bool mixed  = (j0 == ibase);
        const bool bwonly = (j0 < ibase);
        const bool doF = !bwonly;
        const bool doB = mixed || bwonly;

        // ---- exp, mask, store P (bf16 row-major [q][key]) per tile
        #pragma unroll
        for (int t = 0; t < 2; ++t) {
            float p0[4], p1[4];
            #pragma unroll
            for (int r = 0; r < 4; ++r) {
                p0[r] = exp2f(st[t][0][r]);
                p1[r] = exp2f(st[t][1][r]);
            }
            unsigned* PF = Pw + t * 640;
            unsigned* PB = PF + 320;
            if (mixed) {
                const int ig = ibase + 16 * t + col;
                float m0[4], m1[4];
                #pragma unroll
                for (int r = 0; r < 4; ++r) {
                    const int jg = j0 + 4 * quad + r;
                    m0[r] = (jg >= ig) ? p0[r] : 0.f;
                    m1[r] = (jg + 16 >= ig) ? p1[r] : 0.f;
                }
                unsigned* pr = PF + col * 20 + quad * 2;
                pr[0] = pk2(m0[0], m0[1]);
                pr[1] = pk2(m0[2], m0[3]);
                pr[8] = pk2(m1[0], m1[1]);
                pr[9] = pk2(m1[2], m1[3]);
                #pragma unroll
                for (int r = 0; r < 4; ++r) {
                    const int jg = j0 + 4 * quad + r;
                    m0[r] = (jg <= ig) ? p0[r] : 0.f;
                    m1[r] = (jg + 16 <= ig) ? p1[r] : 0.f;
                }
                pr = PB + col * 20 + quad * 2;
                pr[0] = pk2(m0[0], m0[1]);
                pr[1] = pk2(m0[2], m0[3]);
                pr[8] = pk2(m1[0], m1[1]);
                pr[9] = pk2(m1[2], m1[3]);
            } else {
                unsigned* pr = (bwonly ? PB : PF) + col * 20 + quad * 2;
                pr[0] = pk2(p0[0], p0[1]);
                pr[1] = pk2(p0[2], p0[3]);
                pr[8] = pk2(p1[0], p1[1]);
                pr[9] = pk2(p1[2], p1[3]);
            }
        }

        // ---- PV: O^T[s] += V^T · P^T ; l[s] += ones · P^T
        #pragma unroll
        for (int t = 0; t < 2; ++t) {
            if (doF) {
                Frag pf; pf.u4 = *(const uint4*)(Pw + t * 640 + col * 20 + quad * 4);
                lacc[t][0] = MFMA16(ones.s, pf.s, lacc[t][0]);
                #pragma unroll
                for (int c = 0; c < 4; ++c) ot[t][0][c] = MFMA16(vf[c].s, pf.s, ot[t][0][c]);
            }
            if (doB) {
                Frag pg; pg.u4 = *(const uint4*)(Pw + t * 640 + 320 + col * 20 + quad * 4);
                lacc[t][1] = MFMA16(ones.s, pg.s, lacc[t][1]);
                #pragma unroll
                for (int c = 0; c < 4; ++c) ot[t][1][c] = MFMA16(vf[c].s, pg.s, ot[t][1][c]);
            }
        }

        // rotate double buffer
        #pragma unroll
        for (int x = 0; x < 4; ++x) { ka[x] = kan[x]; vf[x] = vfn[x]; }
    }

    // ---- cross-wave reduction (two passes over LDS: side 0, then side 1)
    float* red  = (float*)lds;            // [4 w][32 q][68]
    float* lred = (float*)(lds + 8704);   // [4 w][2 s][32 q]
    __syncthreads();

    if (lane < 16) {
        #pragma unroll
        for (int t = 0; t < 2; ++t)
            #pragma unroll
            for (int s = 0; s < 2; ++s)
                lred[(w * 2 + s) * 32 + 16 * t + col] = lacc[t][s][0];
    }
    #pragma unroll
    for (int t = 0; t < 2; ++t)
        #pragma unroll
        for (int c = 0; c < 4; ++c)
            *(f32x4*)&red[(w * 32 + 16 * t + col) * 68 + 16 * c + 4 * quad] = ot[t][0][c];
    __syncthreads();

    const int qo = tid >> 3;          // 0..31
    const int d0 = (tid & 7) * 8;
    float accF[8], accB[8];
    #pragma unroll
    for (int k = 0; k < 8; ++k) accF[k] = 0.f;
    #pragma unroll
    for (int w2 = 0; w2 < 4; ++w2) {
        const float* pr = &red[(w2 * 32 + qo) * 68 + d0];
        #pragma unroll
        for (int k = 0; k < 8; ++k) accF[k] += pr[k];
    }
    float lf = 0.f, lb = 0.f;
    #pragma unroll
    for (int w2 = 0; w2 < 4; ++w2) {
        lf += lred[(w2 * 2 + 0) * 32 + qo];
        lb += lred[(w2 * 2 + 1) * 32 + qo];
    }
    __syncthreads();   // before overwriting red with side 1

    #pragma unroll
    for (int t = 0; t < 2; ++t)
        #pragma unroll
        for (int c = 0; c < 4; ++c)
            *(f32x4*)&red[(w * 32 + 16 * t + col) * 68 + 16 * c + 4 * quad] = ot[t][1][c];
    __syncthreads();

    #pragma unroll
    for (int k = 0; k < 8; ++k) accB[k] = 0.f;
    #pragma unroll
    for (int w2 = 0; w2 < 4; ++w2) {
        const float* pr = &red[(w2 * 32 + qo) * 68 + d0];
        #pragma unroll
        for (int k = 0; k < 8; ++k) accB[k] += pr[k];
    }

    const float rf = 1.0f / lf;
    const float rb = 1.0f / lb;
    float* orow = O + ((size_t)(b * LL + ibase + qo)) * DD + d0;
    float4 o0 = {accF[0] * rf + accB[0] * rb, accF[1] * rf + accB[1] * rb,
                 accF[2] * rf + accB[2] * rb, accF[3] * rf + accB[3] * rb};
    float4 o1 = {accF[4] * rf + accB[4] * rb, accF[5] * rf + accB[5] * rb,
                 accF[6] * rf + accB[6] * rb, accF[7] * rf + accB[7] * rb};
    *(float4*)(orow + 0) = o0;
    *(float4*)(orow + 4) = o1;
}

// ---------------------------------------------- v1 fallback (ws too small) --
__global__ __launch_bounds__(256)
void attn_fused_v1(const float* __restrict__ Q, const float* __restrict__ K,
                   const float* __restrict__ V, float* __restrict__ O) {
    __shared__ unsigned smem[8448];
    const int tid  = threadIdx.x;
    const int w    = tid >> 6;
    const int lane = tid & 63;
    const int col  = lane & 15;
    const int quad = lane >> 4;
    const int b  = blockIdx.x >> 7;
    const int i0 = (blockIdx.x & 127) << 4;
    const float* Qb = Q + (size_t)(b * LL + i0) * DD;
    const float* Kb = K + (size_t)b * LL * DD;
    const float* Vb = V + (size_t)b * LL * DD;
    unsigned* VT = smem + w * 1280;
    unsigned* Pb = smem + 5120 + w * 640;
    Frag qf[2];
    {
        const float* qr = Qb + col * DD + quad * 8;
        float4 a0 = *(const float4*)(qr + 0);
        float4 a1 = *(const float4*)(qr + 4);
        float4 a2 = *(const float4*)(qr + 32);
        float4 a3 = *(const float4*)(qr + 36);
        qf[0].u[0] = pk2(a0.x * QSCALE, a0.y * QSCALE);
        qf[0].u[1] = pk2(a0.z * QSCALE, a0.w * QSCALE);
        qf[0].u[2] = pk2(a1.x * QSCALE, a1.y * QSCALE);
        qf[0].u[3] = pk2(a1.z * QSCALE, a1.w * QSCALE);
        qf[1].u[0] = pk2(a2.x * QSCALE, a2.y * QSCALE);
        qf[1].u[1] = pk2(a2.z * QSCALE, a2.w * QSCALE);
        qf[1].u[2] = pk2(a3.x * QSCALE, a3.y * QSCALE);
        qf[1].u[3] = pk2(a3.z * QSCALE, a3.w * QSCALE);
    }
    Frag ones;
    ones.u[0] = ones.u[1] = ones.u[2] = ones.u[3] = 0x3F803F80u;
    f32x4 zero = {0.f, 0.f, 0.f, 0.f};
    f32x4 ot[2][4];
    f32x4 lacc[2];
    lacc[0] = zero; lacc[1] = zero;
    for (int s = 0; s < 2; ++s)
        for (int c = 0; c < 4; ++c) ot[s][c] = zero;
    const int kbase = w << 9;
    const int dj0   = i0 & ~31;
    for (int blk = 0; blk < 16; ++blk) {
        const int j0 = kbase + (blk << 5);
        Frag ka[2][2];
        for (int f = 0; f < 2; ++f) {
            const float* kr = Kb + (size_t)(j0 + f * 16 + col) * DD + quad * 8;
            float4 c0 = *(const float4*)(kr + 0);
            float4 c1 = *(const float4*)(kr + 4);
            float4 c2 = *(const float4*)(kr + 32);
            float4 c3 = *(const float4*)(kr + 36);
            ka[f][0].u[0] = pk2(c0.x, c0.y);
            ka[f][0].u[1] = pk2(c0.z, c0.w);
            ka[f][0].u[2] = pk2(c1.x, c1.y);
            ka[f][0].u[3] = pk2(c1.z, c1.w);
            ka[f][1].u[0] = pk2(c2.x, c2.y);
            ka[f][1].u[1] = pk2(c2.z, c2.w);
            ka[f][1].u[2] = pk2(c3.x, c3.y);
            ka[f][1].u[3] = pk2(c3.z, c3.w);
        }
        for (int u = 0; u < 4; ++u) {
            const int d0 = u * 16 + quad * 4;
            const float* va = Vb + (size_t)(j0 + 2 * col) * DD + d0;
            float4 x = *(const float4*)(va);
            float4 y = *(const float4*)(va + DD);
            VT[(d0 + 0) * 20 + col] = pk2(x.x, y.x);
            VT[(d0 + 1) * 20 + col] = pk2(x.y, y.y);
            VT[(d0 + 2) * 20 + col] = pk2(x.z, y.z);
            VT[(d0 + 3) * 20 + col] = pk2(x.w, y.w);
        }
        f32x4 st0 = zero, st1 = zero;
        st0 = MFMA16(ka[0][0].s, qf[0].s, st0);
        st0 = MFMA16(ka[0][1].s, qf[1].s, st0);
        st1 = MFMA16(ka[1][0].s, qf[0].s, st1);
        st1 = MFMA16(ka[1][1].s, qf[1].s, st1);
        float p0[4], p1[4];
        for (int r = 0; r < 4; ++r) { p0[r] = exp2f(st0[r]); p1[r] = exp2f(st1[r]); }
        bool doF, doB;
        if (j0 == dj0) {
            const int ig = i0 + col;
            unsigned* prowF = Pb + col * 20 + quad * 2;
            unsigned* prowB = prowF + 320;
            float m0[4], m1[4];
            for (int r = 0; r < 4; ++r) {
                const int jg = j0 + 4 * quad + r;
                m0[r] = (jg >= ig) ? p0[r] : 0.f;
                m1[r] = (jg + 16 >= ig) ? p1[r] : 0.f;
            }
            prowF[0] = pk2(m0[0], m0[1]);
            prowF[1] = pk2(m0[2], m0[3]);
            prowF[8] = pk2(m1[0], m1[1]);
            prowF[9] = pk2(m1[2], m1[3]);
            for (int r = 0; r < 4; ++r) {
                const int jg = j0 + 4 * quad + r;
                m0[r] = (jg <= ig) ? p0[r] : 0.f;
                m1[r] = (jg + 16 <= ig) ? p1[r] : 0.f;
            }
            prowB[0] = pk2(m0[0], m0[1]);
            prowB[1] = pk2(m0[2], m0[3]);
            prowB[8] = pk2(m1[0], m1[1]);
            prowB[9] = pk2(m1[2], m1[3]);
            doF = true; doB = true;
        } else if (j0 < i0) {
            unsigned* prowB = Pb + 320 + col * 20 + quad * 2;
            prowB[0] = pk2(p0[0], p0[1]);
            prowB[1] = pk2(p0[2], p0[3]);
            prowB[8] = pk2(p1[0], p1[1]);
            prowB[9] = pk2(p1[2], p1[3]);
            doF = false; doB = true;
        } else {
            unsigned* prowF = Pb + col * 20 + quad * 2;
            prowF[0] = pk2(p0[0], p0[1]);
            prowF[1] = pk2(p0[2], p0[3]);
            prowF[8] = pk2(p1[0], p1[1]);
            prowF[9] = pk2(p1[2], p1[3]);
            doF = true; doB = false;
        }
        Frag vfr[4];
        for (int c = 0; c < 4; ++c)
            vfr[c].u4 = *(const uint4*)(VT + (16 * c + col) * 20 + quad * 4);
        if (doF) {
            Frag pf; pf.u4 = *(const uint4*)(Pb + col * 20 + quad * 4);
            lacc[0] = MFMA16(ones.s, pf.s, lacc[0]);
            for (int c = 0; c < 4; ++c) ot[0][c] = MFMA16(vfr[c].s, pf.s, ot[0][c]);
        }
        if (doB) {
            Frag pg; pg.u4 = *(const uint4*)(Pb + 320 + col * 20 + quad * 4);
            lacc[1] = MFMA16(ones.s, pg.s, lacc[1]);
            for (int c = 0; c < 4; ++c) ot[1][c] = MFMA16(vfr[c].s, pg.s, ot[1][c]);
        }
    }
    __syncthreads();
    float* red  = (float*)smem;
    float* lred = (float*)(smem + 8192);
    for (int s = 0; s < 2; ++s)
        for (int c = 0; c < 4; ++c)
            for (int r = 0; r < 4; ++r)
                red[((w * 2 + s) * 64 + 16 * c + 4 * quad + r) * 16 + col] = ot[s][c][r];
    if (lane < 16) {
        lred[(w * 2 + 0) * 16 + col] = lacc[0][0];
        lred[(w * 2 + 1) * 16 + col] = lacc[1][0];
    }
    __syncthreads();
    const int ri = tid >> 4;
    const int db = (tid & 15) << 2;
    float lf = 0.f, lb = 0.f;
    for (int w2 = 0; w2 < 4; ++w2) {
        lf += lred[(w2 * 2 + 0) * 16 + ri];
        lb += lred[(w2 * 2 + 1) * 16 + ri];
    }
    const float rf = 1.0f / lf;
    const float rb = 1.0f / lb;
    float acc[4];
    for (int kk = 0; kk < 4; ++kk) {
        float af = 0.f, ab = 0.f;
        for (int w2 = 0; w2 < 4; ++w2) {
            af += red[((w2 * 2 + 0) * 64 + db + kk) * 16 + ri];
            ab += red[((w2 * 2 + 1) * 64 + db + kk) * 16 + ri];
        }
        acc[kk] = af * rf + ab * rb;
    }
    float4 o = {acc[0], acc[1], acc[2], acc[3]};
    *(float4*)(O + (size_t)(b * LL + i0 + ri) * DD + db) = o;
}

extern "C" void kernel_launch(void* const* d_in, const int* in_sizes, int n_in,
                              void* d_out, int out_size, void* d_ws, size_t ws_size,
                              hipStream_t stream) {
    const float* q = (const float*)d_in[0];
    const float* k = (const float*)d_in[1];
    const float* v = (const float*)d_in[2];
    float* o = (float*)d_out;
    (void)in_sizes; (void)n_in; (void)out_size;

    const size_t WS_NEED = (size_t)2 * BB * LL * DD * sizeof(u16t);  // Kp + VTp = 4MB
    if (ws_size >= WS_NEED) {
        u16t* Kp  = (u16t*)d_ws;
        u16t* VTp = Kp + (size_t)BB * LL * DD;
        prepack<<<dim3(512), dim3(256), 0, stream>>>(k, v, Kp, VTp);
        attn_v2<<<dim3(512), dim3(256), 0, stream>>>(q, Kp, VTp, o);
    } else {
        attn_fused_v1<<<dim3(BB * (LL / 16)), dim3(256), 0, stream>>>(q, k, v, o);
    }
}

// Round 3
// 86.419 us; speedup vs baseline: 2.1203x; 1.1673x over previous
//
#include <hip/hip_runtime.h>

// SelfAttention: out = softmax(QK^T*s + fw)V + softmax(QK^T*s + bw)V
// B=8, L=2048, D=64, fp32 in/out. bf16 MFMA, no online max (scores bounded;
// -1e9 mask == hard zero in fp32 exp).
//
// v3: - prepack K and V into MFMA *fragment order* (per 32-key block, per
//       frag, 64 lanes x 16B) -> every hot-loop load is a wave-contiguous
//       1KB dwordx4; packed K+V = 4MB total, L2-resident.
//     - P's C-layout -> B-layout transform done IN REGISTERS via
//       ds_bpermute (4 pk2 + 8 bperm + 4 cndmask), no LDS round trip.
//       Main loop: no LDS, no barriers.
//     - 16 q-rows/WG, grid 1024, launch_bounds(256,3) -> 12 waves/CU.
//     - l (softmax denom) via VALU adds, reduced in epilogue.
//
// MFMA 16x16x32 bf16 layouts (validated R1, absmax 1.6e-2):
//   A: elem j of lane l = A[l&15][(l>>4)*8+j]
//   B: elem j of lane l = B[(l>>4)*8+j][l&15]
//   C/D: elem r of lane l = D[(l>>4)*4+r][l&15]
// bperm transform: lane(col,quad) needs P(keys quad*8..+7, q=col); sources are
// C-layout lanes 32*(quad&1)+col (lo regs) and +16 (hi regs), st0 set for
// quad<2, st1 set for quad>=2.

typedef __attribute__((ext_vector_type(8))) short short8;
typedef __attribute__((ext_vector_type(4))) float f32x4;

union Frag {
    short8 s;
    unsigned u[4];
    uint4 u4;
};

#define MFMA16(A, B, C) __builtin_amdgcn_mfma_f32_16x16x32_bf16((A), (B), (C), 0, 0, 0)

static constexpr int BB = 8, LL = 2048, DD = 64;
static constexpr float QSCALE = 0.125f * 1.44269504088896340736f;  // /sqrt(64)*log2(e)

__device__ __forceinline__ unsigned pk2(float a, float b) {
    unsigned ua = __builtin_bit_cast(unsigned, a) + 0x8000u;
    unsigned ub = __builtin_bit_cast(unsigned, b) + 0x8000u;
    return __builtin_amdgcn_perm(ub, ua, 0x07060302u);
}

__device__ __forceinline__ unsigned bperm(int addr, unsigned v) {
    return (unsigned)__builtin_amdgcn_ds_bpermute(addr, (int)v);
}

// ---------------------------------------------------------------- prepack ---
// grid 1024: [0,512) K-frags, [512,1024) V-frags.
// Kf/Vf layout: [b][jblk 0..63][frag 0..3][lane 0..63] x 4 u32 (16B).
//   K frag g=(f<<1)|h: lane(col,quad) = bf16{ K[j0+16f+col][h*32+quad*8+k] }
//   V frag g=c:        lane(col,quad) = bf16{ V[j0+quad*8+k][16c+col] }
__global__ __launch_bounds__(256)
void prepack_frags(const float* __restrict__ K, const float* __restrict__ V,
                   unsigned* __restrict__ Kf, unsigned* __restrict__ Vf) {
    const int t    = threadIdx.x;
    const int lane = t & 63;
    const int col  = lane & 15;
    const int quad = lane >> 4;
    const int g    = t >> 6;
    if (blockIdx.x < 512) {
        const int b = blockIdx.x >> 6, jblk = blockIdx.x & 63, j0 = jblk << 5;
        const int f = g >> 1, h = g & 1;
        const float* src = K + ((size_t)(b * LL) + j0 + 16 * f + col) * DD + h * 32 + quad * 8;
        float4 a0 = *(const float4*)(src);
        float4 a1 = *(const float4*)(src + 4);
        uint4 o = make_uint4(pk2(a0.x, a0.y), pk2(a0.z, a0.w),
                             pk2(a1.x, a1.y), pk2(a1.z, a1.w));
        *(uint4*)(Kf + (size_t)(b * 64 + jblk) * 1024 + t * 4) = o;
    } else {
        const int idx = blockIdx.x - 512;
        const int b = idx >> 6, jblk = idx & 63, j0 = jblk << 5;
        const float* src = V + ((size_t)(b * LL) + j0 + quad * 8) * DD + 16 * g + col;
        float e[8];
        #pragma unroll
        for (int kk = 0; kk < 8; ++kk) e[kk] = src[(size_t)kk * DD];
        uint4 o = make_uint4(pk2(e[0], e[1]), pk2(e[2], e[3]),
                             pk2(e[4], e[5]), pk2(e[6], e[7]));
        *(uint4*)(Vf + (size_t)(b * 64 + jblk) * 1024 + t * 4) = o;
    }
}

// ------------------------------------------------------------------- main ---
__global__ __launch_bounds__(256, 3)
void attn_v3(const float* __restrict__ Q, const unsigned* __restrict__ Kf,
             const unsigned* __restrict__ Vf, float* __restrict__ O) {
    // LDS only for epilogue: red [4w][2s][16q][68d] = 8704 f; lred 512 f.
    __shared__ __align__(16) float red[9216];

    const int tid  = threadIdx.x;
    const int w    = tid >> 6;
    const int lane = tid & 63;
    const int col  = lane & 15;
    const int quad = lane >> 4;

    const int b  = blockIdx.x & 7;     // batch == XCD slot
    const int i0 = (blockIdx.x >> 3) << 4;

    // ---- Q fragments (B operand), pre-scaled
    Frag qf[2];
    {
        const float* qr = Q + ((size_t)(b * LL) + i0 + col) * DD + quad * 8;
        float4 a0 = *(const float4*)(qr + 0);
        float4 a1 = *(const float4*)(qr + 4);
        float4 a2 = *(const float4*)(qr + 32);
        float4 a3 = *(const float4*)(qr + 36);
        qf[0].u[0] = pk2(a0.x * QSCALE, a0.y * QSCALE);
        qf[0].u[1] = pk2(a0.z * QSCALE, a0.w * QSCALE);
        qf[0].u[2] = pk2(a1.x * QSCALE, a1.y * QSCALE);
        qf[0].u[3] = pk2(a1.z * QSCALE, a1.w * QSCALE);
        qf[1].u[0] = pk2(a2.x * QSCALE, a2.y * QSCALE);
        qf[1].u[1] = pk2(a2.z * QSCALE, a2.w * QSCALE);
        qf[1].u[2] = pk2(a3.x * QSCALE, a3.y * QSCALE);
        qf[1].u[3] = pk2(a3.z * QSCALE, a3.w * QSCALE);
    }

    const int kbase = w << 9;
    const int dj0   = i0 & ~31;
    const unsigned* kp = Kf + (size_t)(b * 64 + (kbase >> 5)) * 1024 + lane * 4;
    const unsigned* vp = Vf + (size_t)(b * 64 + (kbase >> 5)) * 1024 + lane * 4;

    f32x4 zero = {0.f, 0.f, 0.f, 0.f};
    f32x4 ot[2][4];
    #pragma unroll
    for (int s = 0; s < 2; ++s)
        #pragma unroll
        for (int c = 0; c < 4; ++c) ot[s][c] = zero;
    float lsumF = 0.f, lsumB = 0.f;

    const int  bpA = (32 * (quad & 1) + col) << 2;   // bperm byte addr (lo half)
    const bool hiq = quad >= 2;                       // use st1-set sources

    // preload block 0
    Frag ka[4], vf[4], kan[4], vfn[4];
    #pragma unroll
    for (int g = 0; g < 4; ++g) {
        ka[g].u4 = *(const uint4*)(kp + g * 256);
        vf[g].u4 = *(const uint4*)(vp + g * 256);
    }

    for (int blk = 0; blk < 16; ++blk) {
        const int j0 = kbase + (blk << 5);
        const int no = ((blk + 1) & 15) << 10;   // next-block u32 offset (wraps)
        #pragma unroll
        for (int g = 0; g < 4; ++g) {
            kan[g].u4 = *(const uint4*)(kp + no + g * 256);
            vfn[g].u4 = *(const uint4*)(vp + no + g * 256);
        }

        // ---- S^T = K · (Qs)^T  (rows=keys, cols=queries)
        f32x4 st0 = zero, st1 = zero;
        st0 = MFMA16(ka[0].s, qf[0].s, st0);
        st0 = MFMA16(ka[1].s, qf[1].s, st0);
        st1 = MFMA16(ka[2].s, qf[0].s, st1);
        st1 = MFMA16(ka[3].s, qf[1].s, st1);

        float p0[4], p1[4];
        #pragma unroll
        for (int r = 0; r < 4; ++r) { p0[r] = exp2f(st0[r]); p1[r] = exp2f(st1[r]); }

        const bool mixed = (j0 == dj0);

        if (j0 >= dj0) {   // forward side (wave-uniform)
            float m0[4], m1[4];
            if (mixed) {
                const int ig = i0 + col;
                #pragma unroll
                for (int r = 0; r < 4; ++r) {
                    const int jg = j0 + 4 * quad + r;
                    m0[r] = (jg >= ig) ? p0[r] : 0.f;
                    m1[r] = (jg + 16 >= ig) ? p1[r] : 0.f;
                }
            } else {
                #pragma unroll
                for (int r = 0; r < 4; ++r) { m0[r] = p0[r]; m1[r] = p1[r]; }
            }
            lsumF += m0[0] + m0[1] + m0[2] + m0[3] + m1[0] + m1[1] + m1[2] + m1[3];
            unsigned x01 = pk2(m0[0], m0[1]), x23 = pk2(m0[2], m0[3]);
            unsigned y01 = pk2(m1[0], m1[1]), y23 = pk2(m1[2], m1[3]);
            unsigned a0 = bperm(bpA, x01),      a1 = bperm(bpA, x23);
            unsigned a2 = bperm(bpA + 64, x01), a3 = bperm(bpA + 64, x23);
            unsigned b0 = bperm(bpA, y01),      b1 = bperm(bpA, y23);
            unsigned b2 = bperm(bpA + 64, y01), b3 = bperm(bpA + 64, y23);
            Frag pf;
            pf.u[0] = hiq ? b0 : a0;
            pf.u[1] = hiq ? b1 : a1;
            pf.u[2] = hiq ? b2 : a2;
            pf.u[3] = hiq ? b3 : a3;
            #pragma unroll
            for (int c = 0; c < 4; ++c) ot[0][c] = MFMA16(vf[c].s, pf.s, ot[0][c]);
        }
        if (j0 <= dj0) {   // backward side (wave-uniform)
            float m0[4], m1[4];
            if (mixed) {
                const int ig = i0 + col;
                #pragma unroll
                for (int r = 0; r < 4; ++r) {
                    const int jg = j0 + 4 * quad + r;
                    m0[r] = (jg <= ig) ? p0[r] : 0.f;
                    m1[r] = (jg + 16 <= ig) ? p1[r] : 0.f;
                }
            } else {
                #pragma unroll
                for (int r = 0; r < 4; ++r) { m0[r] = p0[r]; m1[r] = p1[r]; }
            }
            lsumB += m0[0] + m0[1] + m0[2] + m0[3] + m1[0] + m1[1] + m1[2] + m1[3];
            unsigned x01 = pk2(m0[0], m0[1]), x23 = pk2(m0[2], m0[3]);
            unsigned y01 = pk2(m1[0], m1[1]), y23 = pk2(m1[2], m1[3]);
            unsigned a0 = bperm(bpA, x01),      a1 = bperm(bpA, x23);
            unsigned a2 = bperm(bpA + 64, x01), a3 = bperm(bpA + 64, x23);
            unsigned b0 = bperm(bpA, y01),      b1 = bperm(bpA, y23);
            unsigned b2 = bperm(bpA + 64, y01), b3 = bperm(bpA + 64, y23);
            Frag pg;
            pg.u[0] = hiq ? b0 : a0;
            pg.u[1] = hiq ? b1 : a1;
            pg.u[2] = hiq ? b2 : a2;
            pg.u[3] = hiq ? b3 : a3;
            #pragma unroll
            for (int c = 0; c < 4; ++c) ot[1][c] = MFMA16(vf[c].s, pg.s, ot[1][c]);
        }

        #pragma unroll
        for (int g = 0; g < 4; ++g) { ka[g] = kan[g]; vf[g] = vfn[g]; }
    }

    // ---- cross-wave reduction
    #pragma unroll
    for (int s = 0; s < 2; ++s)
        #pragma unroll
        for (int c = 0; c < 4; ++c)
            *(f32x4*)&red[((w * 2 + s) * 16 + col) * 68 + 16 * c + 4 * quad] = ot[s][c];
    red[8704 + ((w * 2 + 0) * 4 + quad) * 16 + col] = lsumF;
    red[8704 + ((w * 2 + 1) * 4 + quad) * 16 + col] = lsumB;
    __syncthreads();

    const int q  = tid >> 4;            // 0..15
    const int d0 = (tid & 15) << 2;     // 0..60
    float lf = 0.f, lb = 0.f;
    #pragma unroll
    for (int w2 = 0; w2 < 4; ++w2)
        #pragma unroll
        for (int qd = 0; qd < 4; ++qd) {
            lf += red[8704 + ((w2 * 2 + 0) * 4 + qd) * 16 + q];
            lb += red[8704 + ((w2 * 2 + 1) * 4 + qd) * 16 + q];
        }
    f32x4 aF = {0.f, 0.f, 0.f, 0.f}, aB = aF;
    #pragma unroll
    for (int w2 = 0; w2 < 4; ++w2) {
        aF += *(const f32x4*)&red[((w2 * 2 + 0) * 16 + q) * 68 + d0];
        aB += *(const f32x4*)&red[((w2 * 2 + 1) * 16 + q) * 68 + d0];
    }
    const float rf = 1.0f / lf;
    const float rb = 1.0f / lb;
    float4 o = {aF[0] * rf + aB[0] * rb, aF[1] * rf + aB[1] * rb,
                aF[2] * rf + aB[2] * rb, aF[3] * rf + aB[3] * rb};
    *(float4*)(O + ((size_t)(b * LL) + i0 + q) * DD + d0) = o;
}

// ---------------------------------------------- v1 fallback (ws too small) --
__global__ __launch_bounds__(256)
void attn_fused_v1(const float* __restrict__ Q, const float* __restrict__ K,
                   const float* __restrict__ V, float* __restrict__ O) {
    __shared__ unsigned smem[8448];
    const int tid  = threadIdx.x;
    const int w    = tid >> 6;
    const int lane = tid & 63;
    const int col  = lane & 15;
    const int quad = lane >> 4;
    const int b  = blockIdx.x >> 7;
    const int i0 = (blockIdx.x & 127) << 4;
    const float* Qb = Q + (size_t)(b * LL + i0) * DD;
    const float* Kb = K + (size_t)b * LL * DD;
    const float* Vb = V + (size_t)b * LL * DD;
    unsigned* VT = smem + w * 1280;
    unsigned* Pb = smem + 5120 + w * 640;
    Frag qf[2];
    {
        const float* qr = Qb + col * DD + quad * 8;
        float4 a0 = *(const float4*)(qr + 0);
        float4 a1 = *(const float4*)(qr + 4);
        float4 a2 = *(const float4*)(qr + 32);
        float4 a3 = *(const float4*)(qr + 36);
        qf[0].u[0] = pk2(a0.x * QSCALE, a0.y * QSCALE);
        qf[0].u[1] = pk2(a0.z * QSCALE, a0.w * QSCALE);
        qf[0].u[2] = pk2(a1.x * QSCALE, a1.y * QSCALE);
        qf[0].u[3] = pk2(a1.z * QSCALE, a1.w * QSCALE);
        qf[1].u[0] = pk2(a2.x * QSCALE, a2.y * QSCALE);
        qf[1].u[1] = pk2(a2.z * QSCALE, a2.w * QSCALE);
        qf[1].u[2] = pk2(a3.x * QSCALE, a3.y * QSCALE);
        qf[1].u[3] = pk2(a3.z * QSCALE, a3.w * QSCALE);
    }
    Frag ones;
    ones.u[0] = ones.u[1] = ones.u[2] = ones.u[3] = 0x3F803F80u;
    f32x4 zero = {0.f, 0.f, 0.f, 0.f};
    f32x4 ot[2][4];
    f32x4 lacc[2];
    lacc[0] = zero; lacc[1] = zero;
    for (int s = 0; s < 2; ++s)
        for (int c = 0; c < 4; ++c) ot[s][c] = zero;
    const int kbase = w << 9;
    const int dj0   = i0 & ~31;
    for (int blk = 0; blk < 16; ++blk) {
        const int j0 = kbase + (blk << 5);
        Frag ka[2][2];
        for (int f = 0; f < 2; ++f) {
            const float* kr = Kb + (size_t)(j0 + f * 16 + col) * DD + quad * 8;
            float4 c0 = *(const float4*)(kr + 0);
            float4 c1 = *(const float4*)(kr + 4);
            float4 c2 = *(const float4*)(kr + 32);
            float4 c3 = *(const float4*)(kr + 36);
            ka[f][0].u[0] = pk2(c0.x, c0.y);
            ka[f][0].u[1] = pk2(c0.z, c0.w);
            ka[f][0].u[2] = pk2(c1.x, c1.y);
            ka[f][0].u[3] = pk2(c1.z, c1.w);
            ka[f][1].u[0] = pk2(c2.x, c2.y);
            ka[f][1].u[1] = pk2(c2.z, c2.w);
            ka[f][1].u[2] = pk2(c3.x, c3.y);
            ka[f][1].u[3] = pk2(c3.z, c3.w);
        }
        for (int u = 0; u < 4; ++u) {
            const int d0 = u * 16 + quad * 4;
            const float* va = Vb + (size_t)(j0 + 2 * col) * DD + d0;
            float4 x = *(const float4*)(va);
            float4 y = *(const float4*)(va + DD);
            VT[(d0 + 0) * 20 + col] = pk2(x.x, y.x);
            VT[(d0 + 1) * 20 + col] = pk2(x.y, y.y);
            VT[(d0 + 2) * 20 + col] = pk2(x.z, y.z);
            VT[(d0 + 3) * 20 + col] = pk2(x.w, y.w);
        }
        f32x4 st0 = zero, st1 = zero;
        st0 = MFMA16(ka[0][0].s, qf[0].s, st0);
        st0 = MFMA16(ka[0][1].s, qf[1].s, st0);
        st1 = MFMA16(ka[1][0].s, qf[0].s, st1);
        st1 = MFMA16(ka[1][1].s, qf[1].s, st1);
        float p0[4], p1[4];
        for (int r = 0; r < 4; ++r) { p0[r] = exp2f(st0[r]); p1[r] = exp2f(st1[r]); }
        bool doF, doB;
        if (j0 == dj0) {
            const int ig = i0 + col;
            unsigned* prowF = Pb + col * 20 + quad * 2;
            unsigned* prowB = prowF + 320;
            float m0[4], m1[4];
            for (int r = 0; r < 4; ++r) {
                const int jg = j0 + 4 * quad + r;
                m0[r] = (jg >= ig) ? p0[r] : 0.f;
                m1[r] = (jg + 16 >= ig) ? p1[r] : 0.f;
            }
            prowF[0] = pk2(m0[0], m0[1]);
            prowF[1] = pk2(m0[2], m0[3]);
            prowF[8] = pk2(m1[0], m1[1]);
            prowF[9] = pk2(m1[2], m1[3]);
            for (int r = 0; r < 4; ++r) {
                const int jg = j0 + 4 * quad + r;
                m0[r] = (jg <= ig) ? p0[r] : 0.f;
                m1[r] = (jg + 16 <= ig) ? p1[r] : 0.f;
            }
            prowB[0] = pk2(m0[0], m0[1]);
            prowB[1] = pk2(m0[2], m0[3]);
            prowB[8] = pk2(m1[0], m1[1]);
            prowB[9] = pk2(m1[2], m1[3]);
            doF = true; doB = true;
        } else if (j0 < i0) {
            unsigned* prowB = Pb + 320 + col * 20 + quad * 2;
            prowB[0] = pk2(p0[0], p0[1]);
            prowB[1] = pk2(p0[2], p0[3]);
            prowB[8] = pk2(p1[0], p1[1]);
            prowB[9] = pk2(p1[2], p1[3]);
            doF = false; doB = true;
        } else {
            unsigned* prowF = Pb + col * 20 + quad * 2;
            prowF[0] = pk2(p0[0], p0[1]);
            prowF[1] = pk2(p0[2], p0[3]);
            prowF[8] = pk2(p1[0], p1[1]);
            prowF[9] = pk2(p1[2], p1[3]);
            doF = true; doB = false;
        }
        Frag vfr[4];
        for (int c = 0; c < 4; ++c)
            vfr[c].u4 = *(const uint4*)(VT + (16 * c + col) * 20 + quad * 4);
        if (doF) {
            Frag pf; pf.u4 = *(const uint4*)(Pb + col * 20 + quad * 4);
            lacc[0] = MFMA16(ones.s, pf.s, lacc[0]);
            for (int c = 0; c < 4; ++c) ot[0][c] = MFMA16(vfr[c].s, pf.s, ot[0][c]);
        }
        if (doB) {
            Frag pg; pg.u4 = *(const uint4*)(Pb + 320 + col * 20 + quad * 4);
            lacc[1] = MFMA16(ones.s, pg.s, lacc[1]);
            for (int c = 0; c < 4; ++c) ot[1][c] = MFMA16(vfr[c].s, pg.s, ot[1][c]);
        }
    }
    __syncthreads();
    float* red  = (float*)smem;
    float* lred = (float*)(smem + 8192);
    for (int s = 0; s < 2; ++s)
        for (int c = 0; c < 4; ++c)
            for (int r = 0; r < 4; ++r)
                red[((w * 2 + s) * 64 + 16 * c + 4 * quad + r) * 16 + col] = ot[s][c][r];
    if (lane < 16) {
        lred[(w * 2 + 0) * 16 + col] = lacc[0][0];
        lred[(w * 2 + 1) * 16 + col] = lacc[1][0];
    }
    __syncthreads();
    const int ri = tid >> 4;
    const int db = (tid & 15) << 2;
    float lf = 0.f, lb = 0.f;
    for (int w2 = 0; w2 < 4; ++w2) {
        lf += lred[(w2 * 2 + 0) * 16 + ri];
        lb += lred[(w2 * 2 + 1) * 16 + ri];
    }
    const float rf = 1.0f / lf;
    const float rb = 1.0f / lb;
    float acc[4];
    for (int kk = 0; kk < 4; ++kk) {
        float af = 0.f, ab = 0.f;
        for (int w2 = 0; w2 < 4; ++w2) {
            af += red[((w2 * 2 + 0) * 64 + db + kk) * 16 + ri];
            ab += red[((w2 * 2 + 1) * 64 + db + kk) * 16 + ri];
        }
        acc[kk] = af * rf + ab * rb;
    }
    float4 o = {acc[0], acc[1], acc[2], acc[3]};
    *(float4*)(O + (size_t)(b * LL + i0 + ri) * DD + db) = o;
}

extern "C" void kernel_launch(void* const* d_in, const int* in_sizes, int n_in,
                              void* d_out, int out_size, void* d_ws, size_t ws_size,
                              hipStream_t stream) {
    const float* q = (const float*)d_in[0];
    const float* k = (const float*)d_in[1];
    const float* v = (const float*)d_in[2];
    float* o = (float*)d_out;
    (void)in_sizes; (void)n_in; (void)out_size;

    // Kf + Vf: each [8][64][4][64] x 16B = 2MB -> 4MB total
    const size_t WS_NEED = (size_t)2 * BB * 64 * 1024 * 4 * sizeof(unsigned);
    if (ws_size >= WS_NEED) {
        unsigned* Kf = (unsigned*)d_ws;
        unsigned* Vf = Kf + (size_t)BB * 64 * 1024;
        prepack_frags<<<dim3(1024), dim3(256), 0, stream>>>(k, v, Kf, Vf);
        attn_v3<<<dim3(1024), dim3(256), 0, stream>>>(q, Kf, Vf, o);
    } else {
        attn_fused_v1<<<dim3(BB * (LL / 16)), dim3(256), 0, stream>>>(q, k, v, o);
    }
}